// Round 13
// baseline (289.562 us; speedup 1.0000x reference)
//
#include <hip/hip_runtime.h>

#define NN 100000
#define NE 1600000
#define HDIM 64
#define EDIM 32
#define NTT 3
#define ETT 4
#define NTILES 6250
#define LEPS 1e-5f
#define NBKT 782   // ceil(NN / 128) buckets of 128 dst nodes
#define EPB 8192   // edges per radix workgroup
#define NWGA 196   // ceil(NE / EPB)
#define SCAP 4096  // LDS sort capacity
#define NSC (NBKT * NWGA)   // 153272 whist entries
#define SBLK 150            // ceil(NSC / 1024)

typedef _Float16 half2v __attribute__((ext_vector_type(2)));
typedef _Float16 half4v __attribute__((ext_vector_type(4)));
typedef _Float16 half8v __attribute__((ext_vector_type(8)));
typedef float f32x4 __attribute__((ext_vector_type(4)));

// ---- K0: prep weights ----
__global__ void prep_kernel(const float* __restrict__ Wn, const float* __restrict__ fc_w,
                            _Float16* __restrict__ Wp, _Float16* __restrict__ fcp) {
    const int i = blockIdx.x * blockDim.x + threadIdx.x;
    if (i < 6 * HDIM * HDIM) {
        const int lt = i >> 12;
        const int o = (i >> 6) & 63;
        const int d = i & 63;
        Wp[i] = (_Float16)Wn[((size_t)lt * 64 + d) * 64 + o];
    } else if (i < 6 * HDIM * HDIM + HDIM * HDIM) {
        const int j = i - 6 * HDIM * HDIM;
        fcp[j] = (_Float16)fc_w[j];
    }
}

// ---- K1: edge gates, coalesced: 8 lanes per edge ----
__global__ __launch_bounds__(256) void edge_weights_kernel(
        const float* __restrict__ edge_attr,
        const int* __restrict__ eisrc,
        const int* __restrict__ edge_type,
        const float* __restrict__ Wm,
        const float* __restrict__ bm,
        const float* __restrict__ emb,
        int2* __restrict__ ewu) {
    __shared__ float sWm[2 * ETT * EDIM];
    __shared__ float sc[2 * ETT];
    const int tid = threadIdx.x;
    if (tid < 2 * ETT * EDIM) sWm[tid] = Wm[tid];
    __syncthreads();
    if (tid < 2 * ETT) {
        float c = bm[tid];
        #pragma unroll
        for (int k = 0; k < EDIM; k++) c += emb[tid * EDIM + k] * sWm[tid * EDIM + k];
        sc[tid] = c;
    }
    __syncthreads();
    const int lane = tid & 63;
    const int wv = tid >> 6;
    const int sub = lane >> 3;
    const int k = lane & 7;
    const int ebase = blockIdx.x * 128 + wv * 32;
    #pragma unroll
    for (int it = 0; it < 4; it++) {
        const int e = ebase + it * 8 + sub;
        const int et = edge_type[e];
        const float4 v = ((const float4*)(edge_attr + (size_t)e * EDIM))[k];
        const float4 a = ((const float4*)(sWm + et * EDIM))[k];
        const float4 b = ((const float4*)(sWm + (ETT + et) * EDIM))[k];
        float d0 = v.x * a.x + v.y * a.y + v.z * a.z + v.w * a.w;
        float d1 = v.x * b.x + v.y * b.y + v.z * b.z + v.w * b.w;
        d0 += __shfl_xor(d0, 1); d1 += __shfl_xor(d1, 1);
        d0 += __shfl_xor(d0, 2); d1 += __shfl_xor(d1, 2);
        d0 += __shfl_xor(d0, 4); d1 += __shfl_xor(d1, 4);
        if (k == 0) {
            d0 += sc[et];
            d1 += sc[ETT + et];
            const float w0 = fmaxf(d0, 0.f) + log1pf(expf(-fabsf(d0)));
            const float w1 = fmaxf(d1, 0.f) + log1pf(expf(-fabsf(d1)));
            union { half2v h; int i; } u;
            u.h[0] = (_Float16)w0;
            u.h[1] = (_Float16)w1;
            ewu[e] = make_int2(u.i, eisrc[e]);
        }
    }
}

// ---- K3: x -> fp16 ----
__global__ void xcvt_kernel(const float* __restrict__ x, _Float16* __restrict__ xs) {
    const int i = blockIdx.x * blockDim.x + threadIdx.x;
    const float4 v = ((const float4*)x)[i];
    half4v o = { (_Float16)v.x, (_Float16)v.y, (_Float16)v.z, (_Float16)v.w };
    ((half4v*)xs)[i] = o;
}

// ---- K4a: per-WG LDS histogram by dst bucket ----
__global__ __launch_bounds__(256) void hist_kernel(const int* __restrict__ eidst,
                                                   int* __restrict__ whist) {
    __shared__ int h[NBKT];
    for (int i = threadIdx.x; i < NBKT; i += 256) h[i] = 0;
    __syncthreads();
    const int wg = blockIdx.x;
    const int start = wg * EPB, end = min(start + EPB, NE);
    for (int e = start + threadIdx.x; e < end; e += 256)
        atomicAdd(&h[eidst[e] >> 7], 1);
    __syncthreads();
    for (int i = threadIdx.x; i < NBKT; i += 256) whist[i * NWGA + wg] = h[i];
}

// ---- K4b: 3-level parallel exclusive scan of whist ----
__global__ __launch_bounds__(256) void partial2_kernel(const int* __restrict__ in,
                                                       int* __restrict__ psum) {
    __shared__ int red[256];
    const int b = blockIdx.x, t = threadIdx.x;
    const int base = b * 1024 + t * 4;
    int s = 0;
    #pragma unroll
    for (int k = 0; k < 4; k++) { const int i = base + k; if (i < NSC) s += in[i]; }
    red[t] = s;
    __syncthreads();
    for (int d = 128; d > 0; d >>= 1) {
        if (t < d) red[t] += red[t + d];
        __syncthreads();
    }
    if (t == 0) psum[b] = red[0];
}

__global__ void bscan2_kernel(const int* __restrict__ psum, int* __restrict__ poff) {
    __shared__ int v[256];
    const int t = threadIdx.x;
    v[t] = (t < SBLK) ? psum[t] : 0;
    __syncthreads();
    for (int d = 1; d < 256; d <<= 1) {
        const int x = (t >= d) ? v[t - d] : 0;
        __syncthreads();
        v[t] += x;
        __syncthreads();
    }
    poff[t] = (t == 0) ? 0 : v[t - 1];
}

__global__ __launch_bounds__(256) void wscan2_kernel(const int* __restrict__ in,
                                                     const int* __restrict__ poff,
                                                     int* __restrict__ out) {
    __shared__ int red[256];
    const int b = blockIdx.x, t = threadIdx.x;
    const int base = b * 1024 + t * 4;
    int d4[4];
    #pragma unroll
    for (int k = 0; k < 4; k++) d4[k] = (base + k < NSC) ? in[base + k] : 0;
    const int s = d4[0] + d4[1] + d4[2] + d4[3];
    red[t] = s;
    __syncthreads();
    for (int d = 1; d < 256; d <<= 1) {
        const int x = (t >= d) ? red[t - d] : 0;
        __syncthreads();
        red[t] += x;
        __syncthreads();
    }
    int run = poff[b] + ((t == 0) ? 0 : red[t - 1]);
    #pragma unroll
    for (int k = 0; k < 4; k++) {
        if (base + k < NSC) { out[base + k] = run; run += d4[k]; }
    }
}

// ---- K4c: bucket-grouping scatter via LDS cursors ----
__global__ __launch_bounds__(256) void binb_kernel(const int2* __restrict__ ewu,
                                                   const int* __restrict__ eidst,
                                                   const int* __restrict__ wscan,
                                                   int2* __restrict__ brec) {
    __shared__ int lcur[NBKT];
    const int wg = blockIdx.x;
    for (int i = threadIdx.x; i < NBKT; i += 256) lcur[i] = wscan[i * NWGA + wg];
    __syncthreads();
    const int start = wg * EPB, end = min(start + EPB, NE);
    for (int e = start + threadIdx.x; e < end; e += 256) {
        const int dst = eidst[e];
        const int2 r = ewu[e];
        const int pos = atomicAdd(&lcur[dst >> 7], 1);
        brec[pos] = make_int2(r.x, r.y | ((dst & 127) << 17));
    }
}

// ---- K4d: within-bucket sort to CSR order + derive per-node off ----
__global__ __launch_bounds__(256) void sortb_kernel(const int2* __restrict__ brec,
                                                    const int* __restrict__ wscan,
                                                    int* __restrict__ off,
                                                    int2* __restrict__ ews) {
    __shared__ int hist[128];
    __shared__ int excl[128];
    __shared__ int2 sorted[SCAP];
    const int b = blockIdx.x;
    const int node0 = b << 7;
    const int nn = min(128, NN - node0);
    const int base = wscan[b * NWGA];
    const int end = (b < NBKT - 1) ? wscan[(b + 1) * NWGA] : NE;
    const int n = end - base;
    const int t = threadIdx.x;
    if (t < 128) hist[t] = 0;
    __syncthreads();
    for (int i = t; i < n; i += 256)
        atomicAdd(&hist[(brec[base + i].y >> 17) & 127], 1);
    __syncthreads();
    if (t < 128) excl[t] = hist[t];
    __syncthreads();
    for (int d = 1; d < 128; d <<= 1) {
        int v = 0;
        if (t < 128 && t >= d) v = excl[t - d];
        __syncthreads();
        if (t < 128) excl[t] += v;
        __syncthreads();
    }
    if (t < 128) {
        const int ex = excl[t] - hist[t];
        if (t < nn) off[node0 + t] = base + ex;
        hist[t] = ex;
    }
    if (b == NBKT - 1 && t == 0) off[NN] = NE;
    __syncthreads();
    for (int i = t; i < n; i += 256) {
        const int2 r = brec[base + i];
        const int dstl = (r.y >> 17) & 127;
        const int2 o = make_int2(r.x, r.y & 0x1FFFF);
        const int pos = atomicAdd(&hist[dstl], 1);
        if (pos < SCAP) sorted[pos] = o;
        else ews[base + pos] = o;
    }
    __syncthreads();
    const int m = min(n, SCAP);
    for (int i = t; i < m; i += 256) ews[base + i] = sorted[i];
}

// ---- K5/K7: gather, one node per wave, 16 edges in flight (no spill: 4 waves/EU) ----
template<int LAYER>
__global__ __launch_bounds__(256, 4) void gather_kernel(
        const _Float16* __restrict__ xs,
        const int2* __restrict__ ew,
        const int* __restrict__ off,
        _Float16* __restrict__ aggr) {
    const int lane = threadIdx.x & 63;
    const int wid = threadIdx.x >> 6;
    const int p = blockIdx.x * 4 + wid;          // grid covers NN exactly
    const int sub = lane >> 4;                   // edge slot 0..3
    const int fl = lane & 15;                    // feature group (4 features)
    const int lo = off[p], hi = off[p + 1];
    const half4v xt = *(const half4v*)(xs + (size_t)p * HDIM + fl * 4);
    float a0 = 0.f, a1 = 0.f, a2 = 0.f, a3 = 0.f, sw = 0.f;
    for (int base = lo; base < hi; base += 16) {
        const int cap = hi - 1;
        const int j0 = base + sub,      i0 = j0 < cap ? j0 : cap;
        const int j1 = base + 4 + sub,  i1 = j1 < cap ? j1 : cap;
        const int j2 = base + 8 + sub,  i2 = j2 < cap ? j2 : cap;
        const int j3 = base + 12 + sub, i3 = j3 < cap ? j3 : cap;
        const int2 e0 = ew[i0];
        const int2 e1 = ew[i1];
        const int2 e2 = ew[i2];
        const int2 e3 = ew[i3];
        const half4v r0 = *(const half4v*)(xs + (size_t)e0.y * HDIM + fl * 4);
        const half4v r1 = *(const half4v*)(xs + (size_t)e1.y * HDIM + fl * 4);
        const half4v r2 = *(const half4v*)(xs + (size_t)e2.y * HDIM + fl * 4);
        const half4v r3 = *(const half4v*)(xs + (size_t)e3.y * HDIM + fl * 4);
        union { int i; half2v h; } u0, u1, u2, u3;
        u0.i = e0.x; u1.i = e1.x; u2.i = e2.x; u3.i = e3.x;
        const float w0 = (j0 <= cap) ? (float)u0.h[LAYER] : 0.f;
        const float w1 = (j1 <= cap) ? (float)u1.h[LAYER] : 0.f;
        const float w2 = (j2 <= cap) ? (float)u2.h[LAYER] : 0.f;
        const float w3 = (j3 <= cap) ? (float)u3.h[LAYER] : 0.f;
        a0 += w0 * (float)r0[0] + w1 * (float)r1[0] + w2 * (float)r2[0] + w3 * (float)r3[0];
        a1 += w0 * (float)r0[1] + w1 * (float)r1[1] + w2 * (float)r2[1] + w3 * (float)r3[1];
        a2 += w0 * (float)r0[2] + w1 * (float)r1[2] + w2 * (float)r2[2] + w3 * (float)r3[2];
        a3 += w0 * (float)r0[3] + w1 * (float)r1[3] + w2 * (float)r2[3] + w3 * (float)r3[3];
        sw += w0 + w1 + w2 + w3;
    }
    a0 += __shfl_xor(a0, 16); a1 += __shfl_xor(a1, 16);
    a2 += __shfl_xor(a2, 16); a3 += __shfl_xor(a3, 16);
    sw += __shfl_xor(sw, 16);
    a0 += __shfl_xor(a0, 32); a1 += __shfl_xor(a1, 32);
    a2 += __shfl_xor(a2, 32); a3 += __shfl_xor(a3, 32);
    sw += __shfl_xor(sw, 32);
    if (sub == 0) {
        half4v o;
        o[0] = (_Float16)(a0 - sw * (float)xt[0]);
        o[1] = (_Float16)(a1 - sw * (float)xt[1]);
        o[2] = (_Float16)(a2 - sw * (float)xt[2]);
        o[3] = (_Float16)(a3 - sw * (float)xt[3]);
        *(half4v*)(aggr + (size_t)p * HDIM + fl * 4) = o;
    }
}

// ---- K6/K8: update ----
template<int FUSE>
__global__ __launch_bounds__(256) void update_kernel(const _Float16* __restrict__ aggr,
                                                     const int* __restrict__ ntype,
                                                     const _Float16* __restrict__ Wp,
                                                     const float* __restrict__ bnp,
                                                     const float* __restrict__ lng,
                                                     const float* __restrict__ lnb,
                                                     const _Float16* __restrict__ fcp,
                                                     const float* __restrict__ fcb,
                                                     _Float16* __restrict__ xout,
                                                     float* __restrict__ fout) {
    __shared__ float scst[320];
    __shared__ f32x4 sraw[4 * 4608 / 16];
    for (int i = threadIdx.x; i < 320; i += 256)
        scst[i] = (i < 192) ? bnp[i] : ((i < 256) ? lng[i - 192] : lnb[i - 256]);
    __syncthreads();

    const int wid = threadIdx.x >> 6;
    const int lane = threadIdx.x & 63;
    const int tile = blockIdx.x * 4 + wid;
    if (tile >= NTILES) return;
    const int fl = lane & 15;
    const int gq = lane >> 4;
    const size_t R = (size_t)tile * 16;

    const half8v A0 = *(const half8v*)(aggr + (R + fl) * HDIM + gq * 8);
    const half8v A1 = *(const half8v*)(aggr + (R + fl) * HDIM + 32 + gq * 8);
    int nt[4];
    #pragma unroll
    for (int r = 0; r < 4; r++) nt[r] = ntype[R + gq * 4 + r];

    float h[4][4];
    #pragma unroll
    for (int ob = 0; ob < 4; ob++) {
        const int col = ob * 16 + fl;
        f32x4 c[3];
        #pragma unroll
        for (int t = 0; t < 3; t++) {
            const half8v B0 = *(const half8v*)(Wp + t * 4096 + col * 64 + gq * 8);
            const half8v B1 = *(const half8v*)(Wp + t * 4096 + col * 64 + 32 + gq * 8);
            f32x4 z = { 0.f, 0.f, 0.f, 0.f };
            z = __builtin_amdgcn_mfma_f32_16x16x32_f16(A0, B0, z, 0, 0, 0);
            z = __builtin_amdgcn_mfma_f32_16x16x32_f16(A1, B1, z, 0, 0, 0);
            c[t] = z;
        }
        #pragma unroll
        for (int r = 0; r < 4; r++) {
            float v = (nt[r] == 0) ? c[0][r] : ((nt[r] == 1) ? c[1][r] : c[2][r]);
            v += scst[nt[r] * 64 + col];
            h[ob][r] = fmaxf(v, 0.f);
        }
    }

    float mu[4], rs[4];
    #pragma unroll
    for (int r = 0; r < 4; r++) {
        float m = h[0][r] + h[1][r] + h[2][r] + h[3][r];
        m += __shfl_xor(m, 1); m += __shfl_xor(m, 2);
        m += __shfl_xor(m, 4); m += __shfl_xor(m, 8);
        mu[r] = m * (1.f / 64.f);
        const float d0 = h[0][r] - mu[r], d1 = h[1][r] - mu[r];
        const float d2 = h[2][r] - mu[r], d3 = h[3][r] - mu[r];
        float v = d0 * d0 + d1 * d1 + d2 * d2 + d3 * d3;
        v += __shfl_xor(v, 1); v += __shfl_xor(v, 2);
        v += __shfl_xor(v, 4); v += __shfl_xor(v, 8);
        rs[r] = rsqrtf(v * (1.f / 64.f) + LEPS);
    }

    _Float16* wb = (_Float16*)sraw + (size_t)wid * 2304;   // [16][72] f16 view
    #pragma unroll
    for (int ob = 0; ob < 4; ob++) {
        const int col = ob * 16 + fl;
        const float gg = scst[192 + col], bb = scst[256 + col];
        #pragma unroll
        for (int r = 0; r < 4; r++) {
            const float xn = (h[ob][r] - mu[r]) * rs[r] * gg + bb;
            wb[(gq * 4 + r) * 72 + col] = (_Float16)xn;
        }
    }
    __threadfence_block();

    if (!FUSE) {
        const int rr = lane >> 2, cg = lane & 3;
        const half8v o0 = *(const half8v*)(wb + rr * 72 + cg * 16);
        const half8v o1 = *(const half8v*)(wb + rr * 72 + cg * 16 + 8);
        *(half8v*)(xout + (R + rr) * HDIM + cg * 16) = o0;
        *(half8v*)(xout + (R + rr) * HDIM + cg * 16 + 8) = o1;
    } else {
        const half8v FA0 = *(const half8v*)(wb + fl * 72 + gq * 8);
        const half8v FA1 = *(const half8v*)(wb + fl * 72 + 32 + gq * 8);
        float fo[4][4];
        #pragma unroll
        for (int ob = 0; ob < 4; ob++) {
            const int col = ob * 16 + fl;
            const half8v FB0 = *(const half8v*)(fcp + col * 64 + gq * 8);
            const half8v FB1 = *(const half8v*)(fcp + col * 64 + 32 + gq * 8);
            f32x4 z = { 0.f, 0.f, 0.f, 0.f };
            z = __builtin_amdgcn_mfma_f32_16x16x32_f16(FA0, FB0, z, 0, 0, 0);
            z = __builtin_amdgcn_mfma_f32_16x16x32_f16(FA1, FB1, z, 0, 0, 0);
            const float fb = fcb[col];
            #pragma unroll
            for (int r = 0; r < 4; r++) fo[ob][r] = z[r] + fb;
        }
        __threadfence_block();
        float* fb32 = (float*)((char*)sraw + (size_t)wid * 4608);  // [16][68] f32 view
        #pragma unroll
        for (int ob = 0; ob < 4; ob++) {
            const int col = ob * 16 + fl;
            #pragma unroll
            for (int r = 0; r < 4; r++) fb32[(gq * 4 + r) * 68 + col] = fo[ob][r];
        }
        __threadfence_block();
        #pragma unroll
        for (int rr = 0; rr < 16; rr++)
            fout[(R + rr) * HDIM + lane] = fb32[rr * 68 + lane];
    }
}

extern "C" void kernel_launch(void* const* d_in, const int* in_sizes, int n_in,
                              void* d_out, int out_size, void* d_ws, size_t ws_size,
                              hipStream_t stream) {
    const float* x         = (const float*)d_in[0];
    const int*   ei        = (const int*)d_in[1];
    const float* edge_attr = (const float*)d_in[2];
    const int*   node_type = (const int*)d_in[3];
    const int*   edge_type = (const int*)d_in[4];
    const float* Wn        = (const float*)d_in[5];
    const float* bn        = (const float*)d_in[6];
    const float* Wm        = (const float*)d_in[7];
    const float* bm        = (const float*)d_in[8];
    const float* emb       = (const float*)d_in[9];
    const float* ln_g      = (const float*)d_in[10];
    const float* ln_b      = (const float*)d_in[11];
    const float* fc_w      = (const float*)d_in[12];
    const float* fc_b      = (const float*)d_in[13];
    float* out = (float*)d_out;

    char* W = (char*)d_ws;
    int2*      ewu  = (int2*)W;                               // 12.8e6 B
    int2*      ews  = (int2*)(W + 12800000);                  // 12.8e6 B
    _Float16*  xs   = (_Float16*)(W + 25600000);              // 12.8e6 B
    _Float16*  x1s  = (_Float16*)(W + 38400000);              // 12.8e6 B
    int2*      brec = (int2*)(W + 51200000);                  // 12.8e6 B
    _Float16*  aggr = (_Float16*)brec;                        // alias: brec dead after sortb
    char*      p3   = W + 64000000;
    _Float16*  Wp   = (_Float16*)p3;                          // 49152 B
    _Float16*  fcp  = (_Float16*)(p3 + 49152);                // 8192 B
    int*       off  = (int*)(p3 + 49152 + 8192);              // NN+16
    int*       psum2 = off + NN + 16;                         // 256
    int*       poff2 = psum2 + 256;                           // 256
    int*       whist = poff2 + 256;                           // NSC
    int*       wscan = whist + NSC;                           // NSC

    prep_kernel<<<112, 256, 0, stream>>>(Wn, fc_w, Wp, fcp);
    edge_weights_kernel<<<NE / 128, 256, 0, stream>>>(edge_attr, ei, edge_type,
                                                      Wm, bm, emb, ewu);
    xcvt_kernel<<<6250, 256, 0, stream>>>(x, xs);

    // CSR build: WG-local radix; off derived inside sortb
    hist_kernel<<<NWGA, 256, 0, stream>>>(ei + NE, whist);
    partial2_kernel<<<SBLK, 256, 0, stream>>>(whist, psum2);
    bscan2_kernel<<<1, 256, 0, stream>>>(psum2, poff2);
    wscan2_kernel<<<SBLK, 256, 0, stream>>>(whist, poff2, wscan);
    binb_kernel<<<NWGA, 256, 0, stream>>>(ewu, ei + NE, wscan, brec);
    sortb_kernel<<<NBKT, 256, 0, stream>>>(brec, wscan, off, ews);

    // layer 0
    gather_kernel<0><<<NN / 4, 256, 0, stream>>>(xs, ews, off, aggr);
    update_kernel<0><<<(NTILES + 3) / 4, 256, 0, stream>>>(aggr, node_type,
        Wp, bn, ln_g, ln_b, fcp, fc_b, x1s, nullptr);
    // layer 1 (+FC)
    gather_kernel<1><<<NN / 4, 256, 0, stream>>>(x1s, ews, off, aggr);
    update_kernel<1><<<(NTILES + 3) / 4, 256, 0, stream>>>(aggr, node_type,
        Wp + 3 * 4096, bn + NTT * HDIM, ln_g + HDIM, ln_b + HDIM, fcp, fc_b, nullptr, out);
}

// Round 14
// 267.149 us; speedup vs baseline: 1.0839x; 1.0839x over previous
//
#include <hip/hip_runtime.h>

#define NN 100000
#define NE 1600000
#define HDIM 64
#define EDIM 32
#define NTT 3
#define ETT 4
#define NTILES 6250
#define LEPS 1e-5f
#define NBKT 782   // ceil(NN / 128) buckets of 128 dst nodes
#define EPB 8192   // edges per radix workgroup
#define NWGA 196   // ceil(NE / EPB)
#define SCAP 4096  // LDS sort capacity
#define NSC (NBKT * NWGA)   // 153272 whist entries
#define SBLK 150            // ceil(NSC / 1024)

typedef _Float16 half2v __attribute__((ext_vector_type(2)));
typedef _Float16 half4v __attribute__((ext_vector_type(4)));
typedef _Float16 half8v __attribute__((ext_vector_type(8)));
typedef float f32x4 __attribute__((ext_vector_type(4)));

// ---- K0: prep weights ----
__global__ void prep_kernel(const float* __restrict__ Wn, const float* __restrict__ fc_w,
                            _Float16* __restrict__ Wp, _Float16* __restrict__ fcp) {
    const int i = blockIdx.x * blockDim.x + threadIdx.x;
    if (i < 6 * HDIM * HDIM) {
        const int lt = i >> 12;
        const int o = (i >> 6) & 63;
        const int d = i & 63;
        Wp[i] = (_Float16)Wn[((size_t)lt * 64 + d) * 64 + o];
    } else if (i < 6 * HDIM * HDIM + HDIM * HDIM) {
        const int j = i - 6 * HDIM * HDIM;
        fcp[j] = (_Float16)fc_w[j];
    }
}

// ---- K1: edge gates, coalesced: 8 lanes per edge ----
__global__ __launch_bounds__(256) void edge_weights_kernel(
        const float* __restrict__ edge_attr,
        const int* __restrict__ eisrc,
        const int* __restrict__ edge_type,
        const float* __restrict__ Wm,
        const float* __restrict__ bm,
        const float* __restrict__ emb,
        int2* __restrict__ ewu) {
    __shared__ float sWm[2 * ETT * EDIM];
    __shared__ float sc[2 * ETT];
    const int tid = threadIdx.x;
    if (tid < 2 * ETT * EDIM) sWm[tid] = Wm[tid];
    __syncthreads();
    if (tid < 2 * ETT) {
        float c = bm[tid];
        #pragma unroll
        for (int k = 0; k < EDIM; k++) c += emb[tid * EDIM + k] * sWm[tid * EDIM + k];
        sc[tid] = c;
    }
    __syncthreads();
    const int lane = tid & 63;
    const int wv = tid >> 6;
    const int sub = lane >> 3;
    const int k = lane & 7;
    const int ebase = blockIdx.x * 128 + wv * 32;
    #pragma unroll
    for (int it = 0; it < 4; it++) {
        const int e = ebase + it * 8 + sub;
        const int et = edge_type[e];
        const float4 v = ((const float4*)(edge_attr + (size_t)e * EDIM))[k];
        const float4 a = ((const float4*)(sWm + et * EDIM))[k];
        const float4 b = ((const float4*)(sWm + (ETT + et) * EDIM))[k];
        float d0 = v.x * a.x + v.y * a.y + v.z * a.z + v.w * a.w;
        float d1 = v.x * b.x + v.y * b.y + v.z * b.z + v.w * b.w;
        d0 += __shfl_xor(d0, 1); d1 += __shfl_xor(d1, 1);
        d0 += __shfl_xor(d0, 2); d1 += __shfl_xor(d1, 2);
        d0 += __shfl_xor(d0, 4); d1 += __shfl_xor(d1, 4);
        if (k == 0) {
            d0 += sc[et];
            d1 += sc[ETT + et];
            const float w0 = fmaxf(d0, 0.f) + log1pf(expf(-fabsf(d0)));
            const float w1 = fmaxf(d1, 0.f) + log1pf(expf(-fabsf(d1)));
            union { half2v h; int i; } u;
            u.h[0] = (_Float16)w0;
            u.h[1] = (_Float16)w1;
            ewu[e] = make_int2(u.i, eisrc[e]);
        }
    }
}

// ---- K3: x -> fp16 ----
__global__ void xcvt_kernel(const float* __restrict__ x, _Float16* __restrict__ xs) {
    const int i = blockIdx.x * blockDim.x + threadIdx.x;
    const float4 v = ((const float4*)x)[i];
    half4v o = { (_Float16)v.x, (_Float16)v.y, (_Float16)v.z, (_Float16)v.w };
    ((half4v*)xs)[i] = o;
}

// ---- K4a: per-WG LDS histogram by dst bucket ----
__global__ __launch_bounds__(256) void hist_kernel(const int* __restrict__ eidst,
                                                   int* __restrict__ whist) {
    __shared__ int h[NBKT];
    for (int i = threadIdx.x; i < NBKT; i += 256) h[i] = 0;
    __syncthreads();
    const int wg = blockIdx.x;
    const int start = wg * EPB, end = min(start + EPB, NE);
    for (int e = start + threadIdx.x; e < end; e += 256)
        atomicAdd(&h[eidst[e] >> 7], 1);
    __syncthreads();
    for (int i = threadIdx.x; i < NBKT; i += 256) whist[i * NWGA + wg] = h[i];
}

// ---- K4b: 3-level parallel exclusive scan of whist ----
__global__ __launch_bounds__(256) void partial2_kernel(const int* __restrict__ in,
                                                       int* __restrict__ psum) {
    __shared__ int red[256];
    const int b = blockIdx.x, t = threadIdx.x;
    const int base = b * 1024 + t * 4;
    int s = 0;
    #pragma unroll
    for (int k = 0; k < 4; k++) { const int i = base + k; if (i < NSC) s += in[i]; }
    red[t] = s;
    __syncthreads();
    for (int d = 128; d > 0; d >>= 1) {
        if (t < d) red[t] += red[t + d];
        __syncthreads();
    }
    if (t == 0) psum[b] = red[0];
}

__global__ void bscan2_kernel(const int* __restrict__ psum, int* __restrict__ poff) {
    __shared__ int v[256];
    const int t = threadIdx.x;
    v[t] = (t < SBLK) ? psum[t] : 0;
    __syncthreads();
    for (int d = 1; d < 256; d <<= 1) {
        const int x = (t >= d) ? v[t - d] : 0;
        __syncthreads();
        v[t] += x;
        __syncthreads();
    }
    poff[t] = (t == 0) ? 0 : v[t - 1];
}

__global__ __launch_bounds__(256) void wscan2_kernel(const int* __restrict__ in,
                                                     const int* __restrict__ poff,
                                                     int* __restrict__ out) {
    __shared__ int red[256];
    const int b = blockIdx.x, t = threadIdx.x;
    const int base = b * 1024 + t * 4;
    int d4[4];
    #pragma unroll
    for (int k = 0; k < 4; k++) d4[k] = (base + k < NSC) ? in[base + k] : 0;
    const int s = d4[0] + d4[1] + d4[2] + d4[3];
    red[t] = s;
    __syncthreads();
    for (int d = 1; d < 256; d <<= 1) {
        const int x = (t >= d) ? red[t - d] : 0;
        __syncthreads();
        red[t] += x;
        __syncthreads();
    }
    int run = poff[b] + ((t == 0) ? 0 : red[t - 1]);
    #pragma unroll
    for (int k = 0; k < 4; k++) {
        if (base + k < NSC) { out[base + k] = run; run += d4[k]; }
    }
}

// ---- K4c: bucket-grouping scatter via LDS cursors ----
__global__ __launch_bounds__(256) void binb_kernel(const int2* __restrict__ ewu,
                                                   const int* __restrict__ eidst,
                                                   const int* __restrict__ wscan,
                                                   int2* __restrict__ brec) {
    __shared__ int lcur[NBKT];
    const int wg = blockIdx.x;
    for (int i = threadIdx.x; i < NBKT; i += 256) lcur[i] = wscan[i * NWGA + wg];
    __syncthreads();
    const int start = wg * EPB, end = min(start + EPB, NE);
    for (int e = start + threadIdx.x; e < end; e += 256) {
        const int dst = eidst[e];
        const int2 r = ewu[e];
        const int pos = atomicAdd(&lcur[dst >> 7], 1);
        brec[pos] = make_int2(r.x, r.y | ((dst & 127) << 17));
    }
}

// ---- K4d: within-bucket sort to CSR order + derive per-node off ----
__global__ __launch_bounds__(256) void sortb_kernel(const int2* __restrict__ brec,
                                                    const int* __restrict__ wscan,
                                                    int* __restrict__ off,
                                                    int2* __restrict__ ews) {
    __shared__ int hist[128];
    __shared__ int excl[128];
    __shared__ int2 sorted[SCAP];
    const int b = blockIdx.x;
    const int node0 = b << 7;
    const int nn = min(128, NN - node0);
    const int base = wscan[b * NWGA];
    const int end = (b < NBKT - 1) ? wscan[(b + 1) * NWGA] : NE;
    const int n = end - base;
    const int t = threadIdx.x;
    if (t < 128) hist[t] = 0;
    __syncthreads();
    for (int i = t; i < n; i += 256)
        atomicAdd(&hist[(brec[base + i].y >> 17) & 127], 1);
    __syncthreads();
    if (t < 128) excl[t] = hist[t];
    __syncthreads();
    for (int d = 1; d < 128; d <<= 1) {
        int v = 0;
        if (t < 128 && t >= d) v = excl[t - d];
        __syncthreads();
        if (t < 128) excl[t] += v;
        __syncthreads();
    }
    if (t < 128) {
        const int ex = excl[t] - hist[t];
        if (t < nn) off[node0 + t] = base + ex;
        hist[t] = ex;
    }
    if (b == NBKT - 1 && t == 0) off[NN] = NE;
    __syncthreads();
    for (int i = t; i < n; i += 256) {
        const int2 r = brec[base + i];
        const int dstl = (r.y >> 17) & 127;
        const int2 o = make_int2(r.x, r.y & 0x1FFFF);
        const int pos = atomicAdd(&hist[dstl], 1);
        if (pos < SCAP) sorted[pos] = o;
        else ews[base + pos] = o;
    }
    __syncthreads();
    const int m = min(n, SCAP);
    for (int i = t; i < m; i += 256) ews[base + i] = sorted[i];
}

// ---- K5/K7: gather — coalesced record prefetch + shuffle distribution ----
// 16 rows per ROWS16; rows' (w,src) come from registers via shuffle, so all
// row loads issue back-to-back with no interleaved ew waits.
#define ROWS16(OFS)                                                        \
    _Pragma("unroll")                                                      \
    for (int g = 0; g < 4; g++) {                                          \
        const int r = (OFS) + g * 4 + sub;                                 \
        const float w = __shfl(rw, r);                                     \
        const int s = __shfl(rs, r);                                       \
        const half4v xv = *(const half4v*)(xs + (size_t)s * HDIM + fl * 4);\
        a0 += w * (float)xv[0]; a1 += w * (float)xv[1];                    \
        a2 += w * (float)xv[2]; a3 += w * (float)xv[3];                    \
        sw += w;                                                           \
    }

template<int LAYER>
__global__ __launch_bounds__(256) void gather_kernel(
        const _Float16* __restrict__ xs,
        const int2* __restrict__ ew,
        const int* __restrict__ off,
        _Float16* __restrict__ aggr) {
    const int lane = threadIdx.x & 63;
    const int wid = threadIdx.x >> 6;
    const int p = blockIdx.x * 4 + wid;          // grid covers NN exactly
    const int sub = lane >> 4;                   // row slot 0..3
    const int fl = lane & 15;                    // feature group (4 features)
    const int lo = off[p], hi = off[p + 1];
    const int deg = hi - lo;
    const half4v xt = *(const half4v*)(xs + (size_t)p * HDIM + fl * 4);

    // prefetch up to 64 edge records in one coalesced load
    const int cl = max(hi - 1, 0);
    const int2 rec = ew[min(lo + lane, cl)];
    union { int i; half2v h; } u; u.i = rec.x;
    float rw = (lo + lane < hi) ? (float)u.h[LAYER] : 0.f;
    int rs = rec.y;

    float a0 = 0.f, a1 = 0.f, a2 = 0.f, a3 = 0.f, sw = 0.f;
    if (deg <= 16) {
        ROWS16(0)
    } else if (deg <= 32) {
        ROWS16(0) ROWS16(16)
    } else {
        ROWS16(0) ROWS16(16) ROWS16(32) ROWS16(48)
        for (int base = lo + 64; base < hi; base += 64) {   // rare deg>64
            const int2 rec2 = ew[min(base + lane, cl)];
            union { int i; half2v h; } u2; u2.i = rec2.x;
            rw = (base + lane < hi) ? (float)u2.h[LAYER] : 0.f;
            rs = rec2.y;
            ROWS16(0) ROWS16(16) ROWS16(32) ROWS16(48)
        }
    }

    // reduce across the 4 row slots (lanes stride 16)
    a0 += __shfl_xor(a0, 16); a1 += __shfl_xor(a1, 16);
    a2 += __shfl_xor(a2, 16); a3 += __shfl_xor(a3, 16);
    sw += __shfl_xor(sw, 16);
    a0 += __shfl_xor(a0, 32); a1 += __shfl_xor(a1, 32);
    a2 += __shfl_xor(a2, 32); a3 += __shfl_xor(a3, 32);
    sw += __shfl_xor(sw, 32);
    if (sub == 0) {
        half4v o;
        o[0] = (_Float16)(a0 - sw * (float)xt[0]);
        o[1] = (_Float16)(a1 - sw * (float)xt[1]);
        o[2] = (_Float16)(a2 - sw * (float)xt[2]);
        o[3] = (_Float16)(a3 - sw * (float)xt[3]);
        *(half4v*)(aggr + (size_t)p * HDIM + fl * 4) = o;
    }
}

// ---- K6/K8: update ----
template<int FUSE>
__global__ __launch_bounds__(256) void update_kernel(const _Float16* __restrict__ aggr,
                                                     const int* __restrict__ ntype,
                                                     const _Float16* __restrict__ Wp,
                                                     const float* __restrict__ bnp,
                                                     const float* __restrict__ lng,
                                                     const float* __restrict__ lnb,
                                                     const _Float16* __restrict__ fcp,
                                                     const float* __restrict__ fcb,
                                                     _Float16* __restrict__ xout,
                                                     float* __restrict__ fout) {
    __shared__ float scst[320];
    __shared__ f32x4 sraw[4 * 4608 / 16];
    for (int i = threadIdx.x; i < 320; i += 256)
        scst[i] = (i < 192) ? bnp[i] : ((i < 256) ? lng[i - 192] : lnb[i - 256]);
    __syncthreads();

    const int wid = threadIdx.x >> 6;
    const int lane = threadIdx.x & 63;
    const int tile = blockIdx.x * 4 + wid;
    if (tile >= NTILES) return;
    const int fl = lane & 15;
    const int gq = lane >> 4;
    const size_t R = (size_t)tile * 16;

    const half8v A0 = *(const half8v*)(aggr + (R + fl) * HDIM + gq * 8);
    const half8v A1 = *(const half8v*)(aggr + (R + fl) * HDIM + 32 + gq * 8);
    int nt[4];
    #pragma unroll
    for (int r = 0; r < 4; r++) nt[r] = ntype[R + gq * 4 + r];

    float h[4][4];
    #pragma unroll
    for (int ob = 0; ob < 4; ob++) {
        const int col = ob * 16 + fl;
        f32x4 c[3];
        #pragma unroll
        for (int t = 0; t < 3; t++) {
            const half8v B0 = *(const half8v*)(Wp + t * 4096 + col * 64 + gq * 8);
            const half8v B1 = *(const half8v*)(Wp + t * 4096 + col * 64 + 32 + gq * 8);
            f32x4 z = { 0.f, 0.f, 0.f, 0.f };
            z = __builtin_amdgcn_mfma_f32_16x16x32_f16(A0, B0, z, 0, 0, 0);
            z = __builtin_amdgcn_mfma_f32_16x16x32_f16(A1, B1, z, 0, 0, 0);
            c[t] = z;
        }
        #pragma unroll
        for (int r = 0; r < 4; r++) {
            float v = (nt[r] == 0) ? c[0][r] : ((nt[r] == 1) ? c[1][r] : c[2][r]);
            v += scst[nt[r] * 64 + col];
            h[ob][r] = fmaxf(v, 0.f);
        }
    }

    float mu[4], rs[4];
    #pragma unroll
    for (int r = 0; r < 4; r++) {
        float m = h[0][r] + h[1][r] + h[2][r] + h[3][r];
        m += __shfl_xor(m, 1); m += __shfl_xor(m, 2);
        m += __shfl_xor(m, 4); m += __shfl_xor(m, 8);
        mu[r] = m * (1.f / 64.f);
        const float d0 = h[0][r] - mu[r], d1 = h[1][r] - mu[r];
        const float d2 = h[2][r] - mu[r], d3 = h[3][r] - mu[r];
        float v = d0 * d0 + d1 * d1 + d2 * d2 + d3 * d3;
        v += __shfl_xor(v, 1); v += __shfl_xor(v, 2);
        v += __shfl_xor(v, 4); v += __shfl_xor(v, 8);
        rs[r] = rsqrtf(v * (1.f / 64.f) + LEPS);
    }

    _Float16* wb = (_Float16*)sraw + (size_t)wid * 2304;   // [16][72] f16 view
    #pragma unroll
    for (int ob = 0; ob < 4; ob++) {
        const int col = ob * 16 + fl;
        const float gg = scst[192 + col], bb = scst[256 + col];
        #pragma unroll
        for (int r = 0; r < 4; r++) {
            const float xn = (h[ob][r] - mu[r]) * rs[r] * gg + bb;
            wb[(gq * 4 + r) * 72 + col] = (_Float16)xn;
        }
    }
    __threadfence_block();

    if (!FUSE) {
        const int rr = lane >> 2, cg = lane & 3;
        const half8v o0 = *(const half8v*)(wb + rr * 72 + cg * 16);
        const half8v o1 = *(const half8v*)(wb + rr * 72 + cg * 16 + 8);
        *(half8v*)(xout + (R + rr) * HDIM + cg * 16) = o0;
        *(half8v*)(xout + (R + rr) * HDIM + cg * 16 + 8) = o1;
    } else {
        const half8v FA0 = *(const half8v*)(wb + fl * 72 + gq * 8);
        const half8v FA1 = *(const half8v*)(wb + fl * 72 + 32 + gq * 8);
        float fo[4][4];
        #pragma unroll
        for (int ob = 0; ob < 4; ob++) {
            const int col = ob * 16 + fl;
            const half8v FB0 = *(const half8v*)(fcp + col * 64 + gq * 8);
            const half8v FB1 = *(const half8v*)(fcp + col * 64 + 32 + gq * 8);
            f32x4 z = { 0.f, 0.f, 0.f, 0.f };
            z = __builtin_amdgcn_mfma_f32_16x16x32_f16(FA0, FB0, z, 0, 0, 0);
            z = __builtin_amdgcn_mfma_f32_16x16x32_f16(FA1, FB1, z, 0, 0, 0);
            const float fb = fcb[col];
            #pragma unroll
            for (int r = 0; r < 4; r++) fo[ob][r] = z[r] + fb;
        }
        __threadfence_block();
        float* fb32 = (float*)((char*)sraw + (size_t)wid * 4608);  // [16][68] f32 view
        #pragma unroll
        for (int ob = 0; ob < 4; ob++) {
            const int col = ob * 16 + fl;
            #pragma unroll
            for (int r = 0; r < 4; r++) fb32[(gq * 4 + r) * 68 + col] = fo[ob][r];
        }
        __threadfence_block();
        #pragma unroll
        for (int rr = 0; rr < 16; rr++)
            fout[(R + rr) * HDIM + lane] = fb32[rr * 68 + lane];
    }
}

extern "C" void kernel_launch(void* const* d_in, const int* in_sizes, int n_in,
                              void* d_out, int out_size, void* d_ws, size_t ws_size,
                              hipStream_t stream) {
    const float* x         = (const float*)d_in[0];
    const int*   ei        = (const int*)d_in[1];
    const float* edge_attr = (const float*)d_in[2];
    const int*   node_type = (const int*)d_in[3];
    const int*   edge_type = (const int*)d_in[4];
    const float* Wn        = (const float*)d_in[5];
    const float* bn        = (const float*)d_in[6];
    const float* Wm        = (const float*)d_in[7];
    const float* bm        = (const float*)d_in[8];
    const float* emb       = (const float*)d_in[9];
    const float* ln_g      = (const float*)d_in[10];
    const float* ln_b      = (const float*)d_in[11];
    const float* fc_w      = (const float*)d_in[12];
    const float* fc_b      = (const float*)d_in[13];
    float* out = (float*)d_out;

    char* W = (char*)d_ws;
    int2*      ewu  = (int2*)W;                               // 12.8e6 B
    int2*      ews  = (int2*)(W + 12800000);                  // 12.8e6 B
    _Float16*  xs   = (_Float16*)(W + 25600000);              // 12.8e6 B
    _Float16*  x1s  = (_Float16*)(W + 38400000);              // 12.8e6 B
    int2*      brec = (int2*)(W + 51200000);                  // 12.8e6 B
    _Float16*  aggr = (_Float16*)brec;                        // alias: brec dead after sortb
    char*      p3   = W + 64000000;
    _Float16*  Wp   = (_Float16*)p3;                          // 49152 B
    _Float16*  fcp  = (_Float16*)(p3 + 49152);                // 8192 B
    int*       off  = (int*)(p3 + 49152 + 8192);              // NN+16
    int*       psum2 = off + NN + 16;                         // 256
    int*       poff2 = psum2 + 256;                           // 256
    int*       whist = poff2 + 256;                           // NSC
    int*       wscan = whist + NSC;                           // NSC

    prep_kernel<<<112, 256, 0, stream>>>(Wn, fc_w, Wp, fcp);
    edge_weights_kernel<<<NE / 128, 256, 0, stream>>>(edge_attr, ei, edge_type,
                                                      Wm, bm, emb, ewu);
    xcvt_kernel<<<6250, 256, 0, stream>>>(x, xs);

    // CSR build: WG-local radix; off derived inside sortb
    hist_kernel<<<NWGA, 256, 0, stream>>>(ei + NE, whist);
    partial2_kernel<<<SBLK, 256, 0, stream>>>(whist, psum2);
    bscan2_kernel<<<1, 256, 0, stream>>>(psum2, poff2);
    wscan2_kernel<<<SBLK, 256, 0, stream>>>(whist, poff2, wscan);
    binb_kernel<<<NWGA, 256, 0, stream>>>(ewu, ei + NE, wscan, brec);
    sortb_kernel<<<NBKT, 256, 0, stream>>>(brec, wscan, off, ews);

    // layer 0
    gather_kernel<0><<<NN / 4, 256, 0, stream>>>(xs, ews, off, aggr);
    update_kernel<0><<<(NTILES + 3) / 4, 256, 0, stream>>>(aggr, node_type,
        Wp, bn, ln_g, ln_b, fcp, fc_b, x1s, nullptr);
    // layer 1 (+FC)
    gather_kernel<1><<<NN / 4, 256, 0, stream>>>(x1s, ews, off, aggr);
    update_kernel<1><<<(NTILES + 3) / 4, 256, 0, stream>>>(aggr, node_type,
        Wp + 3 * 4096, bn + NTT * HDIM, ln_g + HDIM, ln_b + HDIM, fcp, fc_b, nullptr, out);
}